// Round 1
// baseline (72.505 us; speedup 1.0000x reference)
//
#include <hip/hip_runtime.h>

namespace {

constexpr int B = 8, C = 4, H = 512, W = 1024, K = 5;
constexpr int HW = H * W;     // 524288 pixels per (b, c) plane
constexpr int NG = HW / 4;    // float4 groups per plane
constexpr float DV = 0.5f;    // DELTA_V
constexpr float DD = 3.0f;    // DELTA_D

// ws layout (floats):
//   [0   .. 200) sums[b][k][5] = {sum_c0, sum_c1, sum_c2, sum_c3, count}
//   [200 .. 240) var_sums[b][k]
constexpr int SUMS_FLOATS = B * K * 5;   // 200
constexpr int VARS_FLOATS = B * K;       // 40

__device__ __forceinline__ float wave_reduce(float v) {
#pragma unroll
  for (int m = 32; m; m >>= 1) v += __shfl_xor(v, m, 64);
  return v;
}

// Pass 1: per-(b,k) pixel counts and per-channel sums.
__global__ __launch_bounds__(256) void pass1_kernel(
    const float* __restrict__ emb, const int* __restrict__ lab,
    float* __restrict__ sums) {
  const int b = blockIdx.y;
  const float4* __restrict__ ep =
      reinterpret_cast<const float4*>(emb + (size_t)b * C * HW);
  const int4* __restrict__ lp =
      reinterpret_cast<const int4*>(lab + (size_t)b * HW);

  float acc[25];  // [k][{c0,c1,c2,c3,cnt}] flat, compile-time indexed only
#pragma unroll
  for (int i = 0; i < 25; i++) acc[i] = 0.f;

  for (int g = blockIdx.x * blockDim.x + threadIdx.x; g < NG;
       g += gridDim.x * blockDim.x) {
    const int4 l4 = lp[g];
    const float4 e0 = ep[0 * NG + g];
    const float4 e1 = ep[1 * NG + g];
    const float4 e2 = ep[2 * NG + g];
    const float4 e3 = ep[3 * NG + g];
    const int ls[4] = {l4.x, l4.y, l4.z, l4.w};
    const float c0[4] = {e0.x, e0.y, e0.z, e0.w};
    const float c1[4] = {e1.x, e1.y, e1.z, e1.w};
    const float c2[4] = {e2.x, e2.y, e2.z, e2.w};
    const float c3[4] = {e3.x, e3.y, e3.z, e3.w};
#pragma unroll
    for (int j = 0; j < 4; j++) {
      const int l = ls[j];
#pragma unroll
      for (int k = 0; k < K; k++) {  // branchless predicated accumulate
        const float m = (l == k + 1) ? 1.f : 0.f;
        acc[k * 5 + 0] += m * c0[j];
        acc[k * 5 + 1] += m * c1[j];
        acc[k * 5 + 2] += m * c2[j];
        acc[k * 5 + 3] += m * c3[j];
        acc[k * 5 + 4] += m;
      }
    }
  }

  // block reduce: wave shuffle -> LDS -> 25 atomics per block
  __shared__ float red[4][25];
  const int wave = threadIdx.x >> 6, lane = threadIdx.x & 63;
#pragma unroll
  for (int i = 0; i < 25; i++) {
    const float v = wave_reduce(acc[i]);
    if (lane == 0) red[wave][i] = v;
  }
  __syncthreads();
  if (threadIdx.x < 25) {
    const float v = red[0][threadIdx.x] + red[1][threadIdx.x] +
                    red[2][threadIdx.x] + red[3][threadIdx.x];
    atomicAdd(&sums[b * 25 + threadIdx.x], v);
  }
}

// Pass 2: per-pixel relu(||e - mean_lane|| - DV)^2, masked-summed per (b,k).
__global__ __launch_bounds__(256) void pass2_kernel(
    const float* __restrict__ emb, const int* __restrict__ lab,
    const float* __restrict__ sums, float* __restrict__ var_sums) {
  const int b = blockIdx.y;
  __shared__ float sm[K][C];
  if (threadIdx.x < K * C) {
    const int k = threadIdx.x / C, c = threadIdx.x % C;
    const float* s = sums + (b * K + k) * 5;
    sm[k][c] = s[c] / s[4];
  }
  __syncthreads();

  const float4* __restrict__ ep =
      reinterpret_cast<const float4*>(emb + (size_t)b * C * HW);
  const int4* __restrict__ lp =
      reinterpret_cast<const int4*>(lab + (size_t)b * HW);

  float vacc[K] = {0.f, 0.f, 0.f, 0.f, 0.f};

  for (int g = blockIdx.x * blockDim.x + threadIdx.x; g < NG;
       g += gridDim.x * blockDim.x) {
    const int4 l4 = lp[g];
    const float4 e0 = ep[0 * NG + g];
    const float4 e1 = ep[1 * NG + g];
    const float4 e2 = ep[2 * NG + g];
    const float4 e3 = ep[3 * NG + g];
    const int ls[4] = {l4.x, l4.y, l4.z, l4.w};
    const float c0[4] = {e0.x, e0.y, e0.z, e0.w};
    const float c1[4] = {e1.x, e1.y, e1.z, e1.w};
    const float c2[4] = {e2.x, e2.y, e2.z, e2.w};
    const float c3[4] = {e3.x, e3.y, e3.z, e3.w};
#pragma unroll
    for (int j = 0; j < 4; j++) {
      const int l = ls[j];
      const int kk = (l > 0) ? (l - 1) : 0;  // safe LDS index; l==0 masked out
      const float d0 = c0[j] - sm[kk][0];
      const float d1 = c1[j] - sm[kk][1];
      const float d2 = c2[j] - sm[kk][2];
      const float d3 = c3[j] - sm[kk][3];
      const float t =
          fmaxf(sqrtf(d0 * d0 + d1 * d1 + d2 * d2 + d3 * d3) - DV, 0.f);
      const float t2 = t * t;
#pragma unroll
      for (int k = 0; k < K; k++) vacc[k] += (l == k + 1) ? t2 : 0.f;
    }
  }

  __shared__ float red[4][K];
  const int wave = threadIdx.x >> 6, lane = threadIdx.x & 63;
#pragma unroll
  for (int i = 0; i < K; i++) {
    const float v = wave_reduce(vacc[i]);
    if (lane == 0) red[wave][i] = v;
  }
  __syncthreads();
  if (threadIdx.x < K) {
    const float v = red[0][threadIdx.x] + red[1][threadIdx.x] +
                    red[2][threadIdx.x] + red[3][threadIdx.x];
    atomicAdd(&var_sums[b * K + threadIdx.x], v);
  }
}

// Finalize: var term, pairwise-centroid term, faithful running-division scan.
__global__ void finalize_kernel(const float* __restrict__ sums,
                                const float* __restrict__ var_sums,
                                float* __restrict__ out) {
  if (threadIdx.x != 0 || blockIdx.x != 0) return;
  float v = 0.f, d = 0.f;
  for (int b = 0; b < B; b++) {
    float m[K][C], cnt[K];
#pragma unroll
    for (int k = 0; k < K; k++) {
      cnt[k] = sums[(b * K + k) * 5 + 4];
#pragma unroll
      for (int c = 0; c < C; c++) m[k][c] = sums[(b * K + k) * 5 + c] / cnt[k];
    }
    float s = 0.f;
#pragma unroll
    for (int k = 0; k < K; k++) s += var_sums[b * K + k] / cnt[k];
    float p = 0.f;
#pragma unroll
    for (int i = 0; i < K; i++) {
#pragma unroll
      for (int j = 0; j < K; j++) {
        if (i == j) continue;  // diagonal: relu(DD - (0 + DD))^2 == 0
        float dd = 0.f;
#pragma unroll
        for (int c = 0; c < C; c++) {
          const float t = m[i][c] - m[j][c];
          dd += t * t;
        }
        const float r = fmaxf(DD - sqrtf(dd), 0.f);
        p += r * r;
      }
    }
    v = (v + s) / (float)K;
    d = (d + p) / (float)(2 * K * (K - 1));
  }
  out[0] = v / (float)B;
  out[1] = d / (float)B;
}

}  // namespace

extern "C" void kernel_launch(void* const* d_in, const int* in_sizes, int n_in,
                              void* d_out, int out_size, void* d_ws,
                              size_t ws_size, hipStream_t stream) {
  const float* emb = (const float*)d_in[0];
  const int* lab = (const int*)d_in[1];
  float* out = (float*)d_out;
  float* sums = (float*)d_ws;
  float* var_sums = sums + SUMS_FLOATS;

  hipMemsetAsync(d_ws, 0, (SUMS_FLOATS + VARS_FLOATS) * sizeof(float), stream);

  dim3 grid(128, B);
  pass1_kernel<<<grid, 256, 0, stream>>>(emb, lab, sums);
  pass2_kernel<<<grid, 256, 0, stream>>>(emb, lab, sums, var_sums);
  finalize_kernel<<<1, 64, 0, stream>>>(sums, var_sums, out);
}